// Round 15
// baseline (97.184 us; speedup 1.0000x reference)
//
#include <hip/hip_runtime.h>

#define DD 2048
#define BB 16

typedef float f32x4 __attribute__((ext_vector_type(4)));
typedef short bf16x8 __attribute__((ext_vector_type(8)));

static __device__ inline short bfbits(float f) {
    __bf16 h = (__bf16)f;
    return __builtin_bit_cast(short, h);
}

static __device__ inline bf16x8 cvt8(f32x4 a, f32x4 b) {
    bf16x8 r;
#pragma unroll
    for (int e = 0; e < 4; ++e) {
        r[e]     = bfbits(a[e]);
        r[4 + e] = bfbits(b[e]);
    }
    return r;
}

// ---------------------------------------------------------------------------
// gemm (R11 version, unchanged): dual-gate MFMA + fused finalize -> u, dv.
// ---------------------------------------------------------------------------
__global__ __launch_bounds__(512) void gemm_kernel(
    const float* __restrict__ xt, const float* __restrict__ h,
    const float* __restrict__ Wa, const float* __restrict__ Wx,
    const float* __restrict__ ba, const float* __restrict__ bx,
    const float* __restrict__ Lam,
    float* __restrict__ u_ws, float* __restrict__ dv_ws)
{
    const int j0   = blockIdx.x * 8;      // 256 blocks
    const int wv   = threadIdx.x >> 6;    // 0..7 : K-range
    const int lane = threadIdx.x & 63;
    const int mn   = lane & 15;
    const int kc   = lane >> 4;           // 0..3

    const float* wrow = (mn < 8) ? (Wa + (size_t)(j0 + mn) * DD)
                                 : (Wx + (size_t)(j0 + (mn & 7)) * DD);
    const float* xrow = xt + (size_t)mn * DD;
    const int kbase = wv * 256 + kc * 8;

    f32x4 acc = {0.f, 0.f, 0.f, 0.f};
#pragma unroll
    for (int s = 0; s < 8; ++s) {
        const int k = kbase + s * 32;
        const f32x4 wa0 = *(const f32x4*)(wrow + k);
        const f32x4 wa1 = *(const f32x4*)(wrow + k + 4);
        const f32x4 xb0 = *(const f32x4*)(xrow + k);
        const f32x4 xb1 = *(const f32x4*)(xrow + k + 4);
        acc = __builtin_amdgcn_mfma_f32_16x16x32_bf16(cvt8(wa0, wa1), cvt8(xb0, xb1), acc, 0, 0, 0);
    }

    __shared__ float part[8][256];
#pragma unroll
    for (int r = 0; r < 4; ++r) part[wv][lane * 4 + r] = acc[r];
    __syncthreads();

    __shared__ float comb[16][17];        // [row][b], padded
    if (threadIdx.x < 256) {
        const int t = threadIdx.x;
        float s = 0.f;
#pragma unroll
        for (int w = 0; w < 8; ++w) s += part[w][t];
        const int l   = t >> 2;
        const int r   = t & 3;
        const int row = ((l >> 4) << 2) + r;   // 0..15: 0-7 A-gate, 8-15 X-gate
        const int col = l & 15;                // b
        comb[row][col] = s;
    }
    __syncthreads();

    if (threadIdx.x < 128) {
        const int b  = threadIdx.x >> 3;       // 0..15
        const int jr = threadIdx.x & 7;        // 0..7
        const int j  = j0 + jr;
        const float sA = comb[jr][b]     + ba[j];
        const float sX = comb[jr + 8][b] + bx[j];
        const float rt  = 1.f / (1.f + expf(-sA));
        const float itg = 1.f / (1.f + expf(-sX));
        const float log_a = -log1pf(expf(-Lam[j]));    // -softplus(-Lam)
        const float a = expf(log_a * rt * 0.125f);     // / C, C = 8
        const float u = sqrtf(fmaxf(0.f, 1.f - a * a)) * (itg * xt[b * DD + j]);
        const float dv = fmaf(a, h[b * DD + j], u);
        u_ws[b * DD + j]  = u;
        dv_ws[b * DD + j] = dv;
    }
}

// ---------------------------------------------------------------------------
// fill (R11/R6 version, unchanged). NOTE: launched TWICE this round as a
// timing probe — idempotent, so correctness unaffected; the total-duration
// delta vs R11 (60.2) measures the warm fill's standalone duration.
// ---------------------------------------------------------------------------
__global__ __launch_bounds__(256) void fill_kernel(
    const float4* __restrict__ u4, const float* __restrict__ dv,
    float4* __restrict__ out)
{
    const int blk = blockIdx.x;       // 0..4095
    const int b   = blk >> 8;         // 0..15
    const int ig  = blk & 255;        // 0..255
    const int i0  = ig << 3;          // 8 rows starting here
    const int t   = threadIdx.x;

    const float4 v0 = u4[(b << 9) + t];         // j4 = t
    const float4 v1 = u4[(b << 9) + 256 + t];   // j4 = 256 + t

    float4* orow = out + ((size_t)b << 20) + ((size_t)i0 << 9);
#pragma unroll
    for (int r = 0; r < 8; ++r) {
        const int i   = i0 + r;
        const int dj4 = i >> 2;
        float4 w0 = v0, w1 = v1;
        if (dj4 == t) {
            ((float*)&w0)[i & 3] = dv[(b << 11) + i];
        } else if (dj4 == 256 + t) {
            ((float*)&w1)[i & 3] = dv[(b << 11) + i];
        }
        orow[t]       = w0;
        orow[256 + t] = w1;
        orow += DD / 4;
    }
}

extern "C" void kernel_launch(void* const* d_in, const int* in_sizes, int n_in,
                              void* d_out, int out_size, void* d_ws, size_t ws_size,
                              hipStream_t stream) {
    const float* xt  = (const float*)d_in[0];
    const float* h   = (const float*)d_in[1];
    const float* Wa  = (const float*)d_in[2];
    const float* Wx  = (const float*)d_in[3];
    const float* ba  = (const float*)d_in[4];
    const float* bx  = (const float*)d_in[5];
    const float* Lam = (const float*)d_in[6];

    float* u_ws  = (float*)d_ws;          // [B, D]
    float* dv_ws = u_ws + BB * DD;        // [B, D]

    gemm_kernel<<<DD / 8, 512, 0, stream>>>(xt, h, Wa, Wx, ba, bx, Lam, u_ws, dv_ws);
    // Launched twice on purpose: timing probe. Idempotent -> same output.
    fill_kernel<<<BB * (DD / 8), 256, 0, stream>>>((const float4*)u_ws, dv_ws, (float4*)d_out);
    fill_kernel<<<BB * (DD / 8), 256, 0, stream>>>((const float4*)u_ws, dv_ws, (float4*)d_out);
}

// Round 16
// 68.910 us; speedup vs baseline: 1.4103x; 1.4103x over previous
//
#include <hip/hip_runtime.h>

#define DD 2048
#define BB 16

typedef float f32x4 __attribute__((ext_vector_type(4)));
typedef short bf16x8 __attribute__((ext_vector_type(8)));

static __device__ inline short bfbits(float f) {
    __bf16 h = (__bf16)f;
    return __builtin_bit_cast(short, h);
}

static __device__ inline bf16x8 cvt8(f32x4 a, f32x4 b) {
    bf16x8 r;
#pragma unroll
    for (int e = 0; e < 4; ++e) {
        r[e]     = bfbits(a[e]);
        r[4 + e] = bfbits(b[e]);
    }
    return r;
}

// ---------------------------------------------------------------------------
// gemm (R11 version, unchanged): dual-gate MFMA + fused finalize -> u, dv.
// ---------------------------------------------------------------------------
__global__ __launch_bounds__(512) void gemm_kernel(
    const float* __restrict__ xt, const float* __restrict__ h,
    const float* __restrict__ Wa, const float* __restrict__ Wx,
    const float* __restrict__ ba, const float* __restrict__ bx,
    const float* __restrict__ Lam,
    float* __restrict__ u_ws, float* __restrict__ dv_ws)
{
    const int j0   = blockIdx.x * 8;      // 256 blocks
    const int wv   = threadIdx.x >> 6;    // 0..7 : K-range
    const int lane = threadIdx.x & 63;
    const int mn   = lane & 15;
    const int kc   = lane >> 4;           // 0..3

    const float* wrow = (mn < 8) ? (Wa + (size_t)(j0 + mn) * DD)
                                 : (Wx + (size_t)(j0 + (mn & 7)) * DD);
    const float* xrow = xt + (size_t)mn * DD;
    const int kbase = wv * 256 + kc * 8;

    f32x4 acc = {0.f, 0.f, 0.f, 0.f};
#pragma unroll
    for (int s = 0; s < 8; ++s) {
        const int k = kbase + s * 32;
        const f32x4 wa0 = *(const f32x4*)(wrow + k);
        const f32x4 wa1 = *(const f32x4*)(wrow + k + 4);
        const f32x4 xb0 = *(const f32x4*)(xrow + k);
        const f32x4 xb1 = *(const f32x4*)(xrow + k + 4);
        acc = __builtin_amdgcn_mfma_f32_16x16x32_bf16(cvt8(wa0, wa1), cvt8(xb0, xb1), acc, 0, 0, 0);
    }

    __shared__ float part[8][256];
#pragma unroll
    for (int r = 0; r < 4; ++r) part[wv][lane * 4 + r] = acc[r];
    __syncthreads();

    __shared__ float comb[16][17];        // [row][b], padded
    if (threadIdx.x < 256) {
        const int t = threadIdx.x;
        float s = 0.f;
#pragma unroll
        for (int w = 0; w < 8; ++w) s += part[w][t];
        const int l   = t >> 2;
        const int r   = t & 3;
        const int row = ((l >> 4) << 2) + r;   // 0..15: 0-7 A-gate, 8-15 X-gate
        const int col = l & 15;                // b
        comb[row][col] = s;
    }
    __syncthreads();

    if (threadIdx.x < 128) {
        const int b  = threadIdx.x >> 3;       // 0..15
        const int jr = threadIdx.x & 7;        // 0..7
        const int j  = j0 + jr;
        const float sA = comb[jr][b]     + ba[j];
        const float sX = comb[jr + 8][b] + bx[j];
        const float rt  = 1.f / (1.f + expf(-sA));
        const float itg = 1.f / (1.f + expf(-sX));
        const float log_a = -log1pf(expf(-Lam[j]));    // -softplus(-Lam)
        const float a = expf(log_a * rt * 0.125f);     // / C, C = 8
        const float u = sqrtf(fmaxf(0.f, 1.f - a * a)) * (itg * xt[b * DD + j]);
        const float dv = fmaf(a, h[b * DD + j], u);
        u_ws[b * DD + j]  = u;
        dv_ws[b * DD + j] = dv;
    }
}

// ---------------------------------------------------------------------------
// fill v7: R6 shape (4096 blocks x 8 rows — warm-measured at 7.25 TB/s)
// + NONTEMPORAL stores. Theory: timed replays start with L3 full of dirty
// poison lines; cached stores pay an alloc+writeback tax (~2x HBM traffic).
// NT stores skip L3 allocation -> pure 268 MB write stream.
// ---------------------------------------------------------------------------
__global__ __launch_bounds__(256) void fill_kernel(
    const float4* __restrict__ u4, const float* __restrict__ dv,
    float* __restrict__ out)
{
    const int blk = blockIdx.x;       // 0..4095
    const int b   = blk >> 8;         // 0..15
    const int ig  = blk & 255;        // 0..255
    const int i0  = ig << 3;          // 8 rows starting here
    const int t   = threadIdx.x;

    const float4 v0 = u4[(b << 9) + t];         // j4 = t
    const float4 v1 = u4[(b << 9) + 256 + t];   // j4 = 256 + t

    f32x4* orow = (f32x4*)(out + ((size_t)b << 22) + ((size_t)i0 << 11));
#pragma unroll
    for (int r = 0; r < 8; ++r) {
        const int i   = i0 + r;
        const int dj4 = i >> 2;
        float4 w0 = v0, w1 = v1;
        if (dj4 == t) {
            ((float*)&w0)[i & 3] = dv[(b << 11) + i];
        } else if (dj4 == 256 + t) {
            ((float*)&w1)[i & 3] = dv[(b << 11) + i];
        }
        __builtin_nontemporal_store(*(const f32x4*)&w0, &orow[t]);
        __builtin_nontemporal_store(*(const f32x4*)&w1, &orow[256 + t]);
        orow += DD / 4;
    }
}

extern "C" void kernel_launch(void* const* d_in, const int* in_sizes, int n_in,
                              void* d_out, int out_size, void* d_ws, size_t ws_size,
                              hipStream_t stream) {
    const float* xt  = (const float*)d_in[0];
    const float* h   = (const float*)d_in[1];
    const float* Wa  = (const float*)d_in[2];
    const float* Wx  = (const float*)d_in[3];
    const float* ba  = (const float*)d_in[4];
    const float* bx  = (const float*)d_in[5];
    const float* Lam = (const float*)d_in[6];

    float* u_ws  = (float*)d_ws;          // [B, D]
    float* dv_ws = u_ws + BB * DD;        // [B, D]

    gemm_kernel<<<DD / 8, 512, 0, stream>>>(xt, h, Wa, Wx, ba, bx, Lam, u_ws, dv_ws);
    fill_kernel<<<BB * (DD / 8), 256, 0, stream>>>((const float4*)u_ws, dv_ws, (float*)d_out);
}

// Round 17
// 64.875 us; speedup vs baseline: 1.4980x; 1.0622x over previous
//
#include <hip/hip_runtime.h>

#define DD 2048
#define BB 16

typedef float f32x4 __attribute__((ext_vector_type(4)));
typedef short bf16x8 __attribute__((ext_vector_type(8)));

static __device__ inline short bfbits(float f) {
    __bf16 h = (__bf16)f;
    return __builtin_bit_cast(short, h);
}

static __device__ inline bf16x8 cvt8(f32x4 a, f32x4 b) {
    bf16x8 r;
#pragma unroll
    for (int e = 0; e < 4; ++e) {
        r[e]     = bfbits(a[e]);
        r[4 + e] = bfbits(b[e]);
    }
    return r;
}

// ---------------------------------------------------------------------------
// gemm+touch: blocks 0-255 = R11 gemm (unchanged math). Blocks 256-511 =
// pre-touch: zero every 8th row of out (33.5 MB) concurrently with gemm.
// Purpose: trigger L3 evictions of dirty poison lines EARLY (overlapped with
// gemm) and warm each fill block's first-written row. fill overwrites all of
// d_out afterwards, so the zeros never survive.
// ---------------------------------------------------------------------------
__global__ __launch_bounds__(512) void gemm_kernel(
    const float* __restrict__ xt, const float* __restrict__ h,
    const float* __restrict__ Wa, const float* __restrict__ Wx,
    const float* __restrict__ ba, const float* __restrict__ bx,
    const float* __restrict__ Lam,
    float* __restrict__ u_ws, float* __restrict__ dv_ws,
    float4* __restrict__ out)
{
    if (blockIdx.x >= 256) {
        // -------- pre-touch path (no LDS, no syncs) --------
        const int tb = blockIdx.x - 256;   // 0..255
        const int t  = threadIdx.x;        // 0..511 ; row = 512 float4
        const float4 z = make_float4(0.f, 0.f, 0.f, 0.f);
#pragma unroll
        for (int r = 0; r < 16; ++r) {
            const int n = tb * 16 + r;     // 0..4095 : (b, row-group)
            const int b = n >> 8;
            const int i = (n & 255) << 3;  // every 8th row = fill's first row
            out[((size_t)b << 20) + ((size_t)i << 9) + t] = z;
        }
        return;
    }

    // -------- gemm path (R11, unchanged) --------
    const int j0   = blockIdx.x * 8;      // 256 blocks
    const int wv   = threadIdx.x >> 6;    // 0..7 : K-range
    const int lane = threadIdx.x & 63;
    const int mn   = lane & 15;
    const int kc   = lane >> 4;           // 0..3

    const float* wrow = (mn < 8) ? (Wa + (size_t)(j0 + mn) * DD)
                                 : (Wx + (size_t)(j0 + (mn & 7)) * DD);
    const float* xrow = xt + (size_t)mn * DD;
    const int kbase = wv * 256 + kc * 8;

    f32x4 acc = {0.f, 0.f, 0.f, 0.f};
#pragma unroll
    for (int s = 0; s < 8; ++s) {
        const int k = kbase + s * 32;
        const f32x4 wa0 = *(const f32x4*)(wrow + k);
        const f32x4 wa1 = *(const f32x4*)(wrow + k + 4);
        const f32x4 xb0 = *(const f32x4*)(xrow + k);
        const f32x4 xb1 = *(const f32x4*)(xrow + k + 4);
        acc = __builtin_amdgcn_mfma_f32_16x16x32_bf16(cvt8(wa0, wa1), cvt8(xb0, xb1), acc, 0, 0, 0);
    }

    __shared__ float part[8][256];
#pragma unroll
    for (int r = 0; r < 4; ++r) part[wv][lane * 4 + r] = acc[r];
    __syncthreads();

    __shared__ float comb[16][17];        // [row][b], padded
    if (threadIdx.x < 256) {
        const int t = threadIdx.x;
        float s = 0.f;
#pragma unroll
        for (int w = 0; w < 8; ++w) s += part[w][t];
        const int l   = t >> 2;
        const int r   = t & 3;
        const int row = ((l >> 4) << 2) + r;   // 0..15: 0-7 A-gate, 8-15 X-gate
        const int col = l & 15;                // b
        comb[row][col] = s;
    }
    __syncthreads();

    if (threadIdx.x < 128) {
        const int b  = threadIdx.x >> 3;       // 0..15
        const int jr = threadIdx.x & 7;        // 0..7
        const int j  = j0 + jr;
        const float sA = comb[jr][b]     + ba[j];
        const float sX = comb[jr + 8][b] + bx[j];
        const float rt  = 1.f / (1.f + expf(-sA));
        const float itg = 1.f / (1.f + expf(-sX));
        const float log_a = -log1pf(expf(-Lam[j]));    // -softplus(-Lam)
        const float a = expf(log_a * rt * 0.125f);     // / C, C = 8
        const float u = sqrtf(fmaxf(0.f, 1.f - a * a)) * (itg * xt[b * DD + j]);
        const float dv = fmaf(a, h[b * DD + j], u);
        u_ws[b * DD + j]  = u;
        dv_ws[b * DD + j] = dv;
    }
}

// ---------------------------------------------------------------------------
// fill (R11/R6 version, unchanged — warm-measured at 7.25 TB/s).
// ---------------------------------------------------------------------------
__global__ __launch_bounds__(256) void fill_kernel(
    const float4* __restrict__ u4, const float* __restrict__ dv,
    float4* __restrict__ out)
{
    const int blk = blockIdx.x;       // 0..4095
    const int b   = blk >> 8;         // 0..15
    const int ig  = blk & 255;        // 0..255
    const int i0  = ig << 3;          // 8 rows starting here
    const int t   = threadIdx.x;

    const float4 v0 = u4[(b << 9) + t];         // j4 = t
    const float4 v1 = u4[(b << 9) + 256 + t];   // j4 = 256 + t

    float4* orow = out + ((size_t)b << 20) + ((size_t)i0 << 9);
#pragma unroll
    for (int r = 0; r < 8; ++r) {
        const int i   = i0 + r;
        const int dj4 = i >> 2;
        float4 w0 = v0, w1 = v1;
        if (dj4 == t) {
            ((float*)&w0)[i & 3] = dv[(b << 11) + i];
        } else if (dj4 == 256 + t) {
            ((float*)&w1)[i & 3] = dv[(b << 11) + i];
        }
        orow[t]       = w0;
        orow[256 + t] = w1;
        orow += DD / 4;
    }
}

extern "C" void kernel_launch(void* const* d_in, const int* in_sizes, int n_in,
                              void* d_out, int out_size, void* d_ws, size_t ws_size,
                              hipStream_t stream) {
    const float* xt  = (const float*)d_in[0];
    const float* h   = (const float*)d_in[1];
    const float* Wa  = (const float*)d_in[2];
    const float* Wx  = (const float*)d_in[3];
    const float* ba  = (const float*)d_in[4];
    const float* bx  = (const float*)d_in[5];
    const float* Lam = (const float*)d_in[6];

    float* u_ws  = (float*)d_ws;          // [B, D]
    float* dv_ws = u_ws + BB * DD;        // [B, D]

    gemm_kernel<<<512, 512, 0, stream>>>(xt, h, Wa, Wx, ba, bx, Lam,
                                         u_ws, dv_ws, (float4*)d_out);
    fill_kernel<<<BB * (DD / 8), 256, 0, stream>>>((const float4*)u_ws, dv_ws, (float4*)d_out);
}

// Round 18
// 60.258 us; speedup vs baseline: 1.6128x; 1.0766x over previous
//
#include <hip/hip_runtime.h>

#define DD 2048
#define BB 16

typedef float f32x4 __attribute__((ext_vector_type(4)));
typedef short bf16x8 __attribute__((ext_vector_type(8)));

static __device__ inline short bfbits(float f) {
    __bf16 h = (__bf16)f;
    return __builtin_bit_cast(short, h);
}

static __device__ inline bf16x8 cvt8(f32x4 a, f32x4 b) {
    bf16x8 r;
#pragma unroll
    for (int e = 0; e < 4; ++e) {
        r[e]     = bfbits(a[e]);
        r[4 + e] = bfbits(b[e]);
    }
    return r;
}

// ---------------------------------------------------------------------------
// gemm (R11 — best measured): dual-gate MFMA + fused finalize at 1x
// redundancy. Block = 8 output columns; A-frag rows 0-7 = Wa, 8-15 = Wx;
// B = xt. 8 waves split K into 256-ranges; LDS combine; 128 epilogue threads
// finalize (sigmoid/exp) and write u, dv.
// C/D layout (m89-verified): col = lane&15 (b), row = (lane>>4)*4 + reg.
// ---------------------------------------------------------------------------
__global__ __launch_bounds__(512) void gemm_kernel(
    const float* __restrict__ xt, const float* __restrict__ h,
    const float* __restrict__ Wa, const float* __restrict__ Wx,
    const float* __restrict__ ba, const float* __restrict__ bx,
    const float* __restrict__ Lam,
    float* __restrict__ u_ws, float* __restrict__ dv_ws)
{
    const int j0   = blockIdx.x * 8;      // 256 blocks
    const int wv   = threadIdx.x >> 6;    // 0..7 : K-range
    const int lane = threadIdx.x & 63;
    const int mn   = lane & 15;
    const int kc   = lane >> 4;           // 0..3

    const float* wrow = (mn < 8) ? (Wa + (size_t)(j0 + mn) * DD)
                                 : (Wx + (size_t)(j0 + (mn & 7)) * DD);
    const float* xrow = xt + (size_t)mn * DD;
    const int kbase = wv * 256 + kc * 8;

    f32x4 acc = {0.f, 0.f, 0.f, 0.f};
#pragma unroll
    for (int s = 0; s < 8; ++s) {
        const int k = kbase + s * 32;
        const f32x4 wa0 = *(const f32x4*)(wrow + k);
        const f32x4 wa1 = *(const f32x4*)(wrow + k + 4);
        const f32x4 xb0 = *(const f32x4*)(xrow + k);
        const f32x4 xb1 = *(const f32x4*)(xrow + k + 4);
        acc = __builtin_amdgcn_mfma_f32_16x16x32_bf16(cvt8(wa0, wa1), cvt8(xb0, xb1), acc, 0, 0, 0);
    }

    __shared__ float part[8][256];
#pragma unroll
    for (int r = 0; r < 4; ++r) part[wv][lane * 4 + r] = acc[r];
    __syncthreads();

    __shared__ float comb[16][17];        // [row][b], padded
    if (threadIdx.x < 256) {
        const int t = threadIdx.x;
        float s = 0.f;
#pragma unroll
        for (int w = 0; w < 8; ++w) s += part[w][t];
        const int l   = t >> 2;
        const int r   = t & 3;
        const int row = ((l >> 4) << 2) + r;   // 0..15: 0-7 A-gate, 8-15 X-gate
        const int col = l & 15;                // b
        comb[row][col] = s;
    }
    __syncthreads();

    if (threadIdx.x < 128) {
        const int b  = threadIdx.x >> 3;       // 0..15
        const int jr = threadIdx.x & 7;        // 0..7
        const int j  = j0 + jr;
        const float sA = comb[jr][b]     + ba[j];
        const float sX = comb[jr + 8][b] + bx[j];
        const float rt  = 1.f / (1.f + expf(-sA));
        const float itg = 1.f / (1.f + expf(-sX));
        const float log_a = -log1pf(expf(-Lam[j]));    // -softplus(-Lam)
        const float a = expf(log_a * rt * 0.125f);     // / C, C = 8
        const float u = sqrtf(fmaxf(0.f, 1.f - a * a)) * (itg * xt[b * DD + j]);
        const float dv = fmaf(a, h[b * DD + j], u);
        u_ws[b * DD + j]  = u;
        dv_ws[b * DD + j] = dv;
    }
}

// ---------------------------------------------------------------------------
// fill (R11/R6 — best measured; warm-probed at 7.25 TB/s = memset ceiling):
// block = (b, 8 rows); u cached in regs, 16 coalesced float4 stores/thread,
// diagonal patched inline.
// ---------------------------------------------------------------------------
__global__ __launch_bounds__(256) void fill_kernel(
    const float4* __restrict__ u4, const float* __restrict__ dv,
    float4* __restrict__ out)
{
    const int blk = blockIdx.x;       // 0..4095
    const int b   = blk >> 8;         // 0..15
    const int ig  = blk & 255;        // 0..255
    const int i0  = ig << 3;          // 8 rows starting here
    const int t   = threadIdx.x;

    const float4 v0 = u4[(b << 9) + t];         // j4 = t
    const float4 v1 = u4[(b << 9) + 256 + t];   // j4 = 256 + t

    float4* orow = out + ((size_t)b << 20) + ((size_t)i0 << 9);
#pragma unroll
    for (int r = 0; r < 8; ++r) {
        const int i   = i0 + r;
        const int dj4 = i >> 2;
        float4 w0 = v0, w1 = v1;
        if (dj4 == t) {
            ((float*)&w0)[i & 3] = dv[(b << 11) + i];
        } else if (dj4 == 256 + t) {
            ((float*)&w1)[i & 3] = dv[(b << 11) + i];
        }
        orow[t]       = w0;
        orow[256 + t] = w1;
        orow += DD / 4;
    }
}

extern "C" void kernel_launch(void* const* d_in, const int* in_sizes, int n_in,
                              void* d_out, int out_size, void* d_ws, size_t ws_size,
                              hipStream_t stream) {
    const float* xt  = (const float*)d_in[0];
    const float* h   = (const float*)d_in[1];
    const float* Wa  = (const float*)d_in[2];
    const float* Wx  = (const float*)d_in[3];
    const float* ba  = (const float*)d_in[4];
    const float* bx  = (const float*)d_in[5];
    const float* Lam = (const float*)d_in[6];

    float* u_ws  = (float*)d_ws;          // [B, D]
    float* dv_ws = u_ws + BB * DD;        // [B, D]

    gemm_kernel<<<DD / 8, 512, 0, stream>>>(xt, h, Wa, Wx, ba, bx, Lam, u_ws, dv_ws);
    fill_kernel<<<BB * (DD / 8), 256, 0, stream>>>((const float4*)u_ws, dv_ws, (float4*)d_out);
}